// Round 5
// baseline (32.100 us; speedup 1.0000x reference)
//
#include <hip/hip_runtime.h>
#include <hip/hip_bf16.h>

#define BB 4
#define TT 2048
#define DD 128
#define CHK 64
#define NCHK 32            // TT/CHK
#define NCHKS (BB*NCHK)    // 128 chunks total

typedef __attribute__((ext_vector_type(8))) short  bf16x8;
typedef __attribute__((ext_vector_type(4))) float  f32x4;

#define MFMA(a,b,c) __builtin_amdgcn_mfma_f32_16x16x32_bf16(a, b, c, 0, 0, 0)

__device__ __forceinline__ short f2b(float f) {
    union { float f; unsigned u; } x; x.f = f;
    unsigned r = x.u + 0x7fffu + ((x.u >> 16) & 1u);   // RNE
    return (short)(r >> 16);
}
__device__ __forceinline__ float b2f(short s) {
    union { unsigned u; float f; } x; x.u = ((unsigned)(unsigned short)s) << 16;
    return x.f;
}
__device__ __forceinline__ bf16x8 cvt8(const float* p) {
    float4 a = *(const float4*)p, b = *(const float4*)(p + 4);
    bf16x8 r;
    r[0]=f2b(a.x); r[1]=f2b(a.y); r[2]=f2b(a.z); r[3]=f2b(a.w);
    r[4]=f2b(b.x); r[5]=f2b(b.y); r[6]=f2b(b.z); r[7]=f2b(b.w);
    return r;
}

// ---------------------------------------------------------------------------
// K1: block (c, h): phi(k) full -> KfT (for S-GEMM);
//     h==0: also stage Kf row-major -> global, z_c.
//     h==1: also phi(q) full, stage Qf row-major -> global.
//     vT half -> global; S_half = Kf^T V_half -> Ss_g bf16 [c][e][d].
// grid 256 blocks x 256 thr. LDS ~78 KB -> 2 blocks/CU.
// ---------------------------------------------------------------------------
__global__ __launch_bounds__(256) void k1_chunk(const float* __restrict__ q,
                                                const float* __restrict__ kin,
                                                const float* __restrict__ vin,
                                                const float* __restrict__ W,
                                                const float* __restrict__ bias,
                                                short* __restrict__ Ss_g,
                                                float* __restrict__ zc_g,
                                                short* __restrict__ vT_g,
                                                short* __restrict__ Qf_g,
                                                short* __restrict__ Kf_g) {
    int c = blockIdx.x >> 1, h = blockIdx.x & 1;
    const float* qc = q   + (size_t)c * CHK * DD;
    const float* kc = kin + (size_t)c * CHK * DD;
    const float* vc = vin + (size_t)c * CHK * DD;

    __shared__ __align__(16) short Wl  [DD][DD + 8];    // 34816 B
    __shared__ __align__(16) short KfT [DD][CHK + 8];   // 18432 B  (KfT[d][t])
    __shared__ __align__(16) short vT  [CHK][CHK + 8];  // 9216 B   (vT[e_local][t])
    __shared__ __align__(16) short stage[CHK][DD + 8];  // 17408 B  Qf/Kf rowmajor, then Ss bf16

    int tid = threadIdx.x, lane = tid & 63, w = tid >> 6;
    int l15 = lane & 15, l4 = lane >> 4;
    const f32x4 z4 = {0.f, 0.f, 0.f, 0.f};

    // prefetch A-fragments
    bf16x8 afk[4], afq[4];
    {
        int row = 16 * w + l15;
        #pragma unroll
        for (int kk = 0; kk < 4; ++kk) afk[kk] = cvt8(kc + row * DD + kk * 32 + l4 * 8);
        if (h) {
            #pragma unroll
            for (int kk = 0; kk < 4; ++kk) afq[kk] = cvt8(qc + row * DD + kk * 32 + l4 * 8);
        }
    }
    // W fp32 -> LDS bf16 (padded rows)
    #pragma unroll
    for (int it = 0; it < 16; ++it) {
        int i = tid + it * 256;               // 4096 float4s
        int row = i >> 5, c4 = (i & 31) * 4;
        float4 v = *(const float4*)(W + (size_t)row * DD + c4);
        unsigned lo = (unsigned short)f2b(v.x) | ((unsigned)(unsigned short)f2b(v.y) << 16);
        unsigned hi = (unsigned short)f2b(v.z) | ((unsigned)(unsigned short)f2b(v.w) << 16);
        uint2 p; p.x = lo; p.y = hi;
        *(uint2*)&Wl[row][c4] = p;
    }
    // vT half: v[t][64h + e_local] -> vT[e_local][t]
    #pragma unroll
    for (int it = 0; it < 4; ++it) {
        int i = tid + it * 256;               // 1024 float4s
        int t = i >> 4, c4 = (i & 15) * 4;
        float4 vv = *(const float4*)(vc + t * DD + 64 * h + c4);
        vT[c4 + 0][t] = f2b(vv.x); vT[c4 + 1][t] = f2b(vv.y);
        vT[c4 + 2][t] = f2b(vv.z); vT[c4 + 3][t] = f2b(vv.w);
    }
    __syncthreads();

    // phi(k): wave w -> t rows 16w..16w+15, all e
    #pragma unroll
    for (int n = 0; n < 8; ++n) {
        int e = 16 * n + l15;
        f32x4 d = z4;
        #pragma unroll
        for (int kk = 0; kk < 4; ++kk) {
            bf16x8 bw = *(const bf16x8*)&Wl[e][kk * 32 + l4 * 8];
            d = MFMA(afk[kk], bw, d);
        }
        float bv = bias[e];
        #pragma unroll
        for (int j = 0; j < 4; ++j) {
            float zv = d[j] + bv;
            short r = f2b((zv > 0.f) ? (zv + 1.f) : __expf(zv));   // ELU+1
            int t = 16 * w + l4 * 4 + j;
            KfT[e][t] = r;
            if (h == 0) stage[t][e] = r;       // Kf row-major
        }
    }
    // phi(q) (h==1 only) -> stage row-major
    if (h) {
        #pragma unroll
        for (int n = 0; n < 8; ++n) {
            int e = 16 * n + l15;
            f32x4 d = z4;
            #pragma unroll
            for (int kk = 0; kk < 4; ++kk) {
                bf16x8 bw = *(const bf16x8*)&Wl[e][kk * 32 + l4 * 8];
                d = MFMA(afq[kk], bw, d);
            }
            float bv = bias[e];
            #pragma unroll
            for (int j = 0; j < 4; ++j) {
                float zv = d[j] + bv;
                stage[16 * w + l4 * 4 + j][e] = f2b((zv > 0.f) ? (zv + 1.f) : __expf(zv));
            }
        }
    }
    __syncthreads();

    // stage -> global (h: Qf, else Kf), 64x128 shorts
    {
        short* dst = (h ? Qf_g : Kf_g) + (size_t)c * CHK * DD;
        #pragma unroll
        for (int it = 0; it < 4; ++it) {
            int i = tid + it * 256;           // 1024 bf16x8 units
            int t = i >> 4, u = (i & 15) * 8;
            *(bf16x8*)(dst + t * DD + u) = *(const bf16x8*)&stage[t][u];
        }
    }
    // z_c (h==0)
    if (h == 0 && tid < DD) {
        float s = 0.f;
        #pragma unroll
        for (int t8 = 0; t8 < CHK / 8; ++t8) {
            bf16x8 kv = *(const bf16x8*)&KfT[tid][t8 * 8];
            #pragma unroll
            for (int j = 0; j < 8; ++j) s += b2f(kv[j]);
        }
        zc_g[(size_t)c * DD + tid] = s;
    }
    // vT half -> global [c][e][t]
    #pragma unroll
    for (int it = 0; it < 2; ++it) {
        int i = tid + it * 256;               // 512 bf16x8
        int e = i >> 3, t0 = (i & 7) * 8;
        *(bf16x8*)(vT_g + (size_t)c * DD * CHK + (64 * h + e) * CHK + t0) =
            *(const bf16x8*)&vT[e][t0];
    }

    // S-GEMM half: S[d][e_local] = sum_t KfT[d][t] * vT[e_local][t]
    f32x4 sacc[2][4];
    #pragma unroll
    for (int mi = 0; mi < 2; ++mi)
        #pragma unroll
        for (int n = 0; n < 4; ++n) sacc[mi][n] = z4;
    #pragma unroll
    for (int kk = 0; kk < 2; ++kk) {
        bf16x8 afr[2];
        #pragma unroll
        for (int mi = 0; mi < 2; ++mi)
            afr[mi] = *(const bf16x8*)&KfT[16 * (2 * w + mi) + l15][kk * 32 + l4 * 8];
        #pragma unroll
        for (int n = 0; n < 4; ++n) {
            bf16x8 bfr = *(const bf16x8*)&vT[16 * n + l15][kk * 32 + l4 * 8];
            sacc[0][n] = MFMA(afr[0], bfr, sacc[0][n]);
            sacc[1][n] = MFMA(afr[1], bfr, sacc[1][n]);
        }
    }
    __syncthreads();   // stage copy-out complete; safe to overwrite

    // sacc -> stage as bf16 Ss[e_local][d]
    #pragma unroll
    for (int mi = 0; mi < 2; ++mi)
        #pragma unroll
        for (int n = 0; n < 4; ++n) {
            int e = 16 * n + l15;
            #pragma unroll
            for (int j = 0; j < 4; ++j)
                stage[e][16 * (2 * w + mi) + l4 * 4 + j] = f2b(sacc[mi][n][j]);
        }
    __syncthreads();

    // stage -> Ss_g bf16 [c][64h+e][d]
    {
        short* dst = Ss_g + (size_t)c * DD * DD + (size_t)(64 * h) * DD;
        #pragma unroll
        for (int it = 0; it < 4; ++it) {
            int i = tid + it * 256;           // 1024 bf16x8
            int e = i >> 4, u = (i & 15) * 8;
            *(bf16x8*)(dst + e * DD + u) = *(const bf16x8*)&stage[e][u];
        }
    }
}

// ---------------------------------------------------------------------------
// K2: exclusive prefix over chunks (bf16 in, bf16 out, fp32 accum).
// grid 512 = (b,e) x 128 thr (thread = d).
// ---------------------------------------------------------------------------
__global__ __launch_bounds__(128) void k2_scan(const short* __restrict__ Ss_g,
                                               const float* __restrict__ zc_g,
                                               short* __restrict__ Sp_g,
                                               float* __restrict__ zp_g) {
    int e = blockIdx.x & 127, b = blockIdx.x >> 7;
    int d = threadIdx.x;
    size_t base = ((size_t)(b * NCHK) * DD + e) * DD + d;
    const size_t stride = (size_t)DD * DD;

    float vals[NCHK];
    #pragma unroll
    for (int c2 = 0; c2 < NCHK; ++c2) vals[c2] = b2f(Ss_g[base + c2 * stride]);
    float run = 0.f;
    #pragma unroll
    for (int c2 = 0; c2 < NCHK; ++c2) {
        Sp_g[base + c2 * stride] = f2b(run);
        run += vals[c2];
    }
    if (e == 0) {
        float vz[NCHK];
        #pragma unroll
        for (int c2 = 0; c2 < NCHK; ++c2) vz[c2] = zc_g[(size_t)(b * NCHK + c2) * DD + d];
        float rz = 0.f;
        #pragma unroll
        for (int c2 = 0; c2 < NCHK; ++c2) {
            zp_g[(size_t)(b * NCHK + c2) * DD + d] = rz;
            rz += vz[c2];
        }
    }
}

// ---------------------------------------------------------------------------
// K3: block (c, h2): e-quarter. No phi, no W. Frags direct from global.
//     P=QK^T causal -> Ps bf16 (LDS); den via virtual zp column MFMA +
//     shfl_xor rowsum; out quarter = Ps@V + Q@Sp; divide; store.
// grid 512 blocks x 256 thr. LDS ~10 KB.
// ---------------------------------------------------------------------------
__global__ __launch_bounds__(256) void k3_out(const short* __restrict__ Qf_g,
                                              const short* __restrict__ Kf_g,
                                              const short* __restrict__ Sp_g,
                                              const float* __restrict__ zp_g,
                                              const short* __restrict__ vT_g,
                                              float* __restrict__ out) {
    int c = blockIdx.x >> 2, h2 = blockIdx.x & 3;

    __shared__ __align__(16) short Ps[CHK][CHK + 8];   // 9216 B
    __shared__ float den[CHK];

    int tid = threadIdx.x, lane = tid & 63, w = tid >> 6;
    int l15 = lane & 15, l4 = lane >> 4;
    const f32x4 z4 = {0.f, 0.f, 0.f, 0.f};

    const short* Qc = Qf_g + (size_t)c * CHK * DD;
    const short* Kc = Kf_g + (size_t)c * CHK * DD;
    const float* zp = zp_g + (size_t)c * DD;

    // A-frags of Q (rows t = 16w + l15)
    bf16x8 aq[4];
    #pragma unroll
    for (int kk = 0; kk < 4; ++kk)
        aq[kk] = *(const bf16x8*)(Qc + (16 * w + l15) * DD + kk * 32 + l4 * 8);

    // virtual zp column B-frags (row l15==0 = zp, else 0)
    bf16x8 bz[4];
    #pragma unroll
    for (int kk = 0; kk < 4; ++kk) {
        bf16x8 zf = cvt8(zp + kk * 32 + l4 * 8);
        bf16x8 zero = {0,0,0,0,0,0,0,0};
        bz[kk] = (l15 == 0) ? zf : zero;
    }

    // QK^T causal -> Ps; in-reg masked rowsum; q.zp via extra MFMA column
    float rs[4] = {0.f, 0.f, 0.f, 0.f};
    f32x4 p4 = z4;
    #pragma unroll
    for (int kk = 0; kk < 4; ++kk) p4 = MFMA(aq[kk], bz[kk], p4);
    #pragma unroll
    for (int n2 = 0; n2 < 4; ++n2) {
        f32x4 p = z4;
        #pragma unroll
        for (int kk = 0; kk < 4; ++kk) {
            bf16x8 bk = *(const bf16x8*)(Kc + (16 * n2 + l15) * DD + kk * 32 + l4 * 8);
            p = MFMA(aq[kk], bk, p);
        }
        int t2 = 16 * n2 + l15;
        #pragma unroll
        for (int j = 0; j < 4; ++j) {
            int t = 16 * w + l4 * 4 + j;
            float pm = (t2 <= t) ? p[j] : 0.f;
            Ps[t][t2] = f2b(pm);
            rs[j] += pm;
        }
    }
    // reduce rowsum across l15 (low 4 lane bits)
    #pragma unroll
    for (int off = 1; off < 16; off <<= 1) {
        #pragma unroll
        for (int j = 0; j < 4; ++j) rs[j] += __shfl_xor(rs[j], off);
    }
    if (l15 == 0) {
        #pragma unroll
        for (int j = 0; j < 4; ++j)
            den[16 * w + l4 * 4 + j] = rs[j] + p4[j] + 1e-6f;
    }
    __syncthreads();

    // out quarter: e = 32*h2 + 16n + l15, n = 0..1
    bf16x8 ap[2];
    #pragma unroll
    for (int kk = 0; kk < 2; ++kk)
        ap[kk] = *(const bf16x8*)&Ps[16 * w + l15][kk * 32 + l4 * 8];

    const short* Sp  = Sp_g + (size_t)c * DD * DD;
    const short* vTg = vT_g + (size_t)c * DD * CHK;
    f32x4 oacc[2];
    oacc[0] = z4; oacc[1] = z4;
    #pragma unroll
    for (int n = 0; n < 2; ++n) {
        int e = 32 * h2 + 16 * n + l15;
        #pragma unroll
        for (int kk = 0; kk < 4; ++kk) {
            bf16x8 bs = *(const bf16x8*)(Sp + e * DD + kk * 32 + l4 * 8);
            oacc[n] = MFMA(aq[kk], bs, oacc[n]);
        }
        #pragma unroll
        for (int kk = 0; kk < 2; ++kk) {
            bf16x8 bv = *(const bf16x8*)(vTg + e * CHK + kk * 32 + l4 * 8);
            oacc[n] = MFMA(ap[kk], bv, oacc[n]);
        }
    }

    float* oc = out + (size_t)c * CHK * DD;
    float invs[4];
    #pragma unroll
    for (int j = 0; j < 4; ++j) invs[j] = 1.0f / den[16 * w + l4 * 4 + j];
    #pragma unroll
    for (int n = 0; n < 2; ++n) {
        int e = 32 * h2 + 16 * n + l15;
        #pragma unroll
        for (int j = 0; j < 4; ++j) {
            int t = 16 * w + l4 * 4 + j;
            oc[t * DD + e] = oacc[n][j] * invs[j];
        }
    }
}

// ---------------------------------------------------------------------------
extern "C" void kernel_launch(void* const* d_in, const int* in_sizes, int n_in,
                              void* d_out, int out_size, void* d_ws, size_t ws_size,
                              hipStream_t stream) {
    const float* q  = (const float*)d_in[0];
    const float* k  = (const float*)d_in[1];
    const float* v  = (const float*)d_in[2];
    const float* W  = (const float*)d_in[3];
    const float* bi = (const float*)d_in[4];
    float* out = (float*)d_out;

    float* zc_g = (float*)d_ws;                         // 16384 f32
    float* zp_g = zc_g + (size_t)NCHKS * DD;            // 16384 f32
    short* Ss_g = (short*)(zp_g + (size_t)NCHKS * DD);  // 2M shorts = 4 MB
    short* Sp_g = Ss_g + (size_t)NCHKS * DD * DD;       // 4 MB
    short* vT_g = Sp_g + (size_t)NCHKS * DD * DD;       // 2 MB
    short* Qf_g = vT_g + (size_t)NCHKS * DD * CHK;      // 2 MB
    short* Kf_g = Qf_g + (size_t)NCHKS * CHK * DD;      // 2 MB

    k1_chunk<<<2 * NCHKS, 256, 0, stream>>>(q, k, v, W, bi, Ss_g, zc_g, vT_g, Qf_g, Kf_g);
    k2_scan<<<512, 128, 0, stream>>>(Ss_g, zc_g, Sp_g, zp_g);
    k3_out<<<4 * NCHKS, 256, 0, stream>>>(Qf_g, Kf_g, Sp_g, zp_g, vT_g, out);
}

// Round 6
// 28.383 us; speedup vs baseline: 1.1309x; 1.1309x over previous
//
#include <hip/hip_runtime.h>
#include <hip/hip_bf16.h>

#define BB 4
#define TT 2048
#define DD 128
#define CHK 64
#define NCHK 32            // TT/CHK
#define NCHKS (BB*NCHK)    // 128 chunks total

typedef __attribute__((ext_vector_type(8))) short  bf16x8;
typedef __attribute__((ext_vector_type(4))) float  f32x4;

#define MFMA(a,b,c) __builtin_amdgcn_mfma_f32_16x16x32_bf16(a, b, c, 0, 0, 0)

__device__ __forceinline__ short f2b(float f) {
    union { float f; unsigned u; } x; x.f = f;
    unsigned r = x.u + 0x7fffu + ((x.u >> 16) & 1u);   // RNE
    return (short)(r >> 16);
}
__device__ __forceinline__ float b2f(short s) {
    union { unsigned u; float f; } x; x.u = ((unsigned)(unsigned short)s) << 16;
    return x.f;
}
__device__ __forceinline__ bf16x8 cvt8(const float* p) {
    float4 a = *(const float4*)p, b = *(const float4*)(p + 4);
    bf16x8 r;
    r[0]=f2b(a.x); r[1]=f2b(a.y); r[2]=f2b(a.z); r[3]=f2b(a.w);
    r[4]=f2b(b.x); r[5]=f2b(b.y); r[6]=f2b(b.z); r[7]=f2b(b.w);
    return r;
}

// W fp32 [128][128] -> LDS bf16 [128][136]
__device__ __forceinline__ void w_to_lds(const float* __restrict__ W,
                                         short (*Wl)[DD + 8], int tid) {
    #pragma unroll
    for (int it = 0; it < 16; ++it) {
        int i = tid + it * 256;               // 4096 float4s
        int row = i >> 5, c4 = (i & 31) * 4;
        float4 v = *(const float4*)(W + (size_t)row * DD + c4);
        unsigned lo = (unsigned short)f2b(v.x) | ((unsigned)(unsigned short)f2b(v.y) << 16);
        unsigned hi = (unsigned short)f2b(v.z) | ((unsigned)(unsigned short)f2b(v.w) << 16);
        uint2 p; p.x = lo; p.y = hi;
        *(uint2*)&Wl[row][c4] = p;
    }
}

// ---------------------------------------------------------------------------
// K1: block (c, h): phi(k) full -> KfT; h==0: stage Kf row-major -> global, z_c;
//     vT half -> global; S_half = Kf^T V_half -> Ss_g bf16 [c][e][d].
// grid 256 x 256. LDS ~79.9 KB -> 2 blocks/CU.
// ---------------------------------------------------------------------------
__global__ __launch_bounds__(256) void k1_chunk(const float* __restrict__ kin,
                                                const float* __restrict__ vin,
                                                const float* __restrict__ W,
                                                const float* __restrict__ bias,
                                                short* __restrict__ Ss_g,
                                                float* __restrict__ zc_g,
                                                short* __restrict__ vT_g,
                                                short* __restrict__ Kf_g) {
    int c = blockIdx.x >> 1, h = blockIdx.x & 1;
    const float* kc = kin + (size_t)c * CHK * DD;
    const float* vc = vin + (size_t)c * CHK * DD;

    __shared__ __align__(16) short Wl  [DD][DD + 8];    // 34816 B
    __shared__ __align__(16) short KfT [DD][CHK + 8];   // 18432 B  (KfT[d][t])
    __shared__ __align__(16) short vT  [CHK][CHK + 8];  // 9216 B   (vT[e_local][t])
    __shared__ __align__(16) short stage[CHK][DD + 8];  // 17408 B  Kf rowmajor, then Ss bf16

    int tid = threadIdx.x, lane = tid & 63, w = tid >> 6;
    int l15 = lane & 15, l4 = lane >> 4;
    const f32x4 z4 = {0.f, 0.f, 0.f, 0.f};

    // prefetch phi(k) A-fragments
    bf16x8 afk[4];
    {
        int row = 16 * w + l15;
        #pragma unroll
        for (int kk = 0; kk < 4; ++kk) afk[kk] = cvt8(kc + row * DD + kk * 32 + l4 * 8);
    }
    w_to_lds(W, Wl, tid);
    // vT half: v[t][64h + e_local] -> vT[e_local][t]
    #pragma unroll
    for (int it = 0; it < 4; ++it) {
        int i = tid + it * 256;               // 1024 float4s
        int t = i >> 4, c4 = (i & 15) * 4;
        float4 vv = *(const float4*)(vc + t * DD + 64 * h + c4);
        vT[c4 + 0][t] = f2b(vv.x); vT[c4 + 1][t] = f2b(vv.y);
        vT[c4 + 2][t] = f2b(vv.z); vT[c4 + 3][t] = f2b(vv.w);
    }
    __syncthreads();

    // phi(k): wave w -> t rows 16w..16w+15, all e
    #pragma unroll
    for (int n = 0; n < 8; ++n) {
        int e = 16 * n + l15;
        f32x4 d = z4;
        #pragma unroll
        for (int kk = 0; kk < 4; ++kk) {
            bf16x8 bw = *(const bf16x8*)&Wl[e][kk * 32 + l4 * 8];
            d = MFMA(afk[kk], bw, d);
        }
        float bv = bias[e];
        #pragma unroll
        for (int j = 0; j < 4; ++j) {
            float zv = d[j] + bv;
            short r = f2b((zv > 0.f) ? (zv + 1.f) : __expf(zv));   // ELU+1
            int t = 16 * w + l4 * 4 + j;
            KfT[e][t] = r;
            if (h == 0) stage[t][e] = r;       // Kf row-major
        }
    }
    __syncthreads();

    if (h == 0) {
        // stage -> Kf_g (coalesced)
        short* dst = Kf_g + (size_t)c * CHK * DD;
        #pragma unroll
        for (int it = 0; it < 4; ++it) {
            int i = tid + it * 256;           // 1024 bf16x8 units
            int t = i >> 4, u = (i & 15) * 8;
            *(bf16x8*)(dst + t * DD + u) = *(const bf16x8*)&stage[t][u];
        }
        // z_c
        if (tid < DD) {
            float s = 0.f;
            #pragma unroll
            for (int t8 = 0; t8 < CHK / 8; ++t8) {
                bf16x8 kv = *(const bf16x8*)&KfT[tid][t8 * 8];
                #pragma unroll
                for (int j = 0; j < 8; ++j) s += b2f(kv[j]);
            }
            zc_g[(size_t)c * DD + tid] = s;
        }
    }
    // vT half -> global [c][e][t]
    #pragma unroll
    for (int it = 0; it < 2; ++it) {
        int i = tid + it * 256;               // 512 bf16x8
        int e = i >> 3, t0 = (i & 7) * 8;
        *(bf16x8*)(vT_g + (size_t)c * DD * CHK + (64 * h + e) * CHK + t0) =
            *(const bf16x8*)&vT[e][t0];
    }

    // S-GEMM half: S[d][e_local] = sum_t KfT[d][t] * vT[e_local][t]
    f32x4 sacc[2][4];
    #pragma unroll
    for (int mi = 0; mi < 2; ++mi)
        #pragma unroll
        for (int n = 0; n < 4; ++n) sacc[mi][n] = z4;
    #pragma unroll
    for (int kk = 0; kk < 2; ++kk) {
        bf16x8 afr[2];
        #pragma unroll
        for (int mi = 0; mi < 2; ++mi)
            afr[mi] = *(const bf16x8*)&KfT[16 * (2 * w + mi) + l15][kk * 32 + l4 * 8];
        #pragma unroll
        for (int n = 0; n < 4; ++n) {
            bf16x8 bfr = *(const bf16x8*)&vT[16 * n + l15][kk * 32 + l4 * 8];
            sacc[0][n] = MFMA(afr[0], bfr, sacc[0][n]);
            sacc[1][n] = MFMA(afr[1], bfr, sacc[1][n]);
        }
    }
    __syncthreads();   // stage copy-out done; safe to overwrite

    // sacc -> stage as bf16 Ss[e_local][d]
    #pragma unroll
    for (int mi = 0; mi < 2; ++mi)
        #pragma unroll
        for (int n = 0; n < 4; ++n) {
            int e = 16 * n + l15;
            #pragma unroll
            for (int j = 0; j < 4; ++j)
                stage[e][16 * (2 * w + mi) + l4 * 4 + j] = f2b(sacc[mi][n][j]);
        }
    __syncthreads();

    // stage -> Ss_g bf16 [c][64h+e][d]
    short* dst = Ss_g + (size_t)c * DD * DD + (size_t)(64 * h) * DD;
    #pragma unroll
    for (int it = 0; it < 4; ++it) {
        int i = tid + it * 256;               // 1024 bf16x8
        int e = i >> 4, u = (i & 15) * 8;
        *(bf16x8*)(dst + e * DD + u) = *(const bf16x8*)&stage[e][u];
    }
}

// ---------------------------------------------------------------------------
// K2: exclusive prefix over chunks (bf16 in/out, fp32 accum).
// grid 512 = (b,e) x 128 thr (thread = d).
// ---------------------------------------------------------------------------
__global__ __launch_bounds__(128) void k2_scan(const short* __restrict__ Ss_g,
                                               const float* __restrict__ zc_g,
                                               short* __restrict__ Sp_g,
                                               float* __restrict__ zp_g) {
    int e = blockIdx.x & 127, b = blockIdx.x >> 7;
    int d = threadIdx.x;
    size_t base = ((size_t)(b * NCHK) * DD + e) * DD + d;
    const size_t stride = (size_t)DD * DD;

    float vals[NCHK];
    #pragma unroll
    for (int c2 = 0; c2 < NCHK; ++c2) vals[c2] = b2f(Ss_g[base + c2 * stride]);
    float run = 0.f;
    #pragma unroll
    for (int c2 = 0; c2 < NCHK; ++c2) {
        Sp_g[base + c2 * stride] = f2b(run);
        run += vals[c2];
    }
    if (e == 0) {
        float vz[NCHK];
        #pragma unroll
        for (int c2 = 0; c2 < NCHK; ++c2) vz[c2] = zc_g[(size_t)(b * NCHK + c2) * DD + d];
        float rz = 0.f;
        #pragma unroll
        for (int c2 = 0; c2 < NCHK; ++c2) {
            zp_g[(size_t)(b * NCHK + c2) * DD + d] = rz;
            rz += vz[c2];
        }
    }
}

// ---------------------------------------------------------------------------
// K3: block (c, h): phi(q) only (W staged); Kf from global -> LDS (coalesced);
//     P=QK^T causal -> Ps bf16; den (wave0); out half = Ps@V + Q@Sp; store.
// grid 256 x 256. LDS ~79.6 KB -> 2 blocks/CU.
// ---------------------------------------------------------------------------
__global__ __launch_bounds__(256) void k3_out(const float* __restrict__ q,
                                              const float* __restrict__ W,
                                              const float* __restrict__ bias,
                                              const short* __restrict__ Kf_g,
                                              const short* __restrict__ Sp_g,
                                              const float* __restrict__ zp_g,
                                              const short* __restrict__ vT_g,
                                              float* __restrict__ out) {
    int c = blockIdx.x >> 1, h = blockIdx.x & 1;

    __shared__ __align__(16) short Wl[DD][DD + 8];     // 34816 B
    __shared__ __align__(16) short Qf[CHK][DD + 8];    // 17408 B
    __shared__ __align__(16) short Kf[CHK][DD + 8];    // 17408 B
    __shared__ __align__(16) short Ps[CHK][CHK + 8];   // 9216 B
    __shared__ float zs[DD];
    __shared__ float den[CHK];

    int tid = threadIdx.x, lane = tid & 63, w = tid >> 6;
    int l15 = lane & 15, l4 = lane >> 4;
    const f32x4 z4 = {0.f, 0.f, 0.f, 0.f};

    if (tid < DD) zs[tid] = zp_g[(size_t)c * DD + tid];

    // prefetch A-frags for phi(q)
    const float* qc = q + (size_t)c * CHK * DD;
    bf16x8 afq[4];
    {
        int row = 16 * w + l15;
        #pragma unroll
        for (int kk = 0; kk < 4; ++kk)
            afq[kk] = cvt8(qc + row * DD + kk * 32 + l4 * 8);
    }
    w_to_lds(W, Wl, tid);
    // Kf global -> LDS (coalesced)
    {
        const short* src = Kf_g + (size_t)c * CHK * DD;
        #pragma unroll
        for (int it = 0; it < 4; ++it) {
            int i = tid + it * 256;           // 1024 bf16x8
            int t = i >> 4, u = (i & 15) * 8;
            *(bf16x8*)&Kf[t][u] = *(const bf16x8*)(src + t * DD + u);
        }
    }
    __syncthreads();

    // phi(q): wave w -> rows 16w..16w+15
    #pragma unroll
    for (int n = 0; n < 8; ++n) {
        int e = 16 * n + l15;
        f32x4 dq = z4;
        #pragma unroll
        for (int kk = 0; kk < 4; ++kk) {
            bf16x8 bw = *(const bf16x8*)&Wl[e][kk * 32 + l4 * 8];
            dq = MFMA(afq[kk], bw, dq);
        }
        float bv = bias[e];
        #pragma unroll
        for (int j = 0; j < 4; ++j) {
            float zq = dq[j] + bv;
            Qf[16 * w + l4 * 4 + j][e] = f2b((zq > 0.f) ? (zq + 1.f) : __expf(zq));
        }
    }
    __syncthreads();

    // QK^T causal -> Ps
    bf16x8 aq[4];
    #pragma unroll
    for (int kk = 0; kk < 4; ++kk)
        aq[kk] = *(const bf16x8*)&Qf[16 * w + l15][kk * 32 + l4 * 8];
    #pragma unroll
    for (int n2 = 0; n2 < 4; ++n2) {
        f32x4 p = z4;
        #pragma unroll
        for (int kk = 0; kk < 4; ++kk) {
            bf16x8 bk = *(const bf16x8*)&Kf[16 * n2 + l15][kk * 32 + l4 * 8];
            p = MFMA(aq[kk], bk, p);
        }
        int t2 = 16 * n2 + l15;
        #pragma unroll
        for (int j = 0; j < 4; ++j) {
            int t = 16 * w + l4 * 4 + j;
            Ps[t][t2] = (t2 <= t) ? f2b(p[j]) : (short)0;
        }
    }
    __syncthreads();

    // den (wave 0, redundant per half-block)
    if (tid < CHK) {
        float s = 1e-6f;
        #pragma unroll
        for (int t8 = 0; t8 < CHK / 8; ++t8) {
            bf16x8 pv = *(const bf16x8*)&Ps[tid][t8 * 8];
            #pragma unroll
            for (int j = 0; j < 8; ++j) s += b2f(pv[j]);
        }
        #pragma unroll
        for (int d8 = 0; d8 < DD / 8; ++d8) {
            bf16x8 qv = *(const bf16x8*)&Qf[tid][d8 * 8];
            #pragma unroll
            for (int j = 0; j < 8; ++j) s += b2f(qv[j]) * zs[d8 * 8 + j];
        }
        den[tid] = s;
    }

    // out half: e = 64h + 16n + l15, n = 0..3
    bf16x8 ap[2];
    #pragma unroll
    for (int kk = 0; kk < 2; ++kk)
        ap[kk] = *(const bf16x8*)&Ps[16 * w + l15][kk * 32 + l4 * 8];

    const short* Sp  = Sp_g + (size_t)c * DD * DD;
    const short* vTg = vT_g + (size_t)c * DD * CHK;
    f32x4 oacc[4];
    #pragma unroll
    for (int n = 0; n < 4; ++n) oacc[n] = z4;
    #pragma unroll
    for (int n = 0; n < 4; ++n) {
        int e = 64 * h + 16 * n + l15;
        #pragma unroll
        for (int kk = 0; kk < 4; ++kk) {
            bf16x8 bs = *(const bf16x8*)(Sp + e * DD + kk * 32 + l4 * 8);
            oacc[n] = MFMA(aq[kk], bs, oacc[n]);
        }
        #pragma unroll
        for (int kk = 0; kk < 2; ++kk) {
            bf16x8 bv = *(const bf16x8*)(vTg + e * CHK + kk * 32 + l4 * 8);
            oacc[n] = MFMA(ap[kk], bv, oacc[n]);
        }
    }
    __syncthreads();   // den ready

    float* oc = out + (size_t)c * CHK * DD;
    float invs[4];
    #pragma unroll
    for (int j = 0; j < 4; ++j) invs[j] = 1.0f / den[16 * w + l4 * 4 + j];
    #pragma unroll
    for (int n = 0; n < 4; ++n) {
        int e = 64 * h + 16 * n + l15;
        #pragma unroll
        for (int j = 0; j < 4; ++j) {
            int t = 16 * w + l4 * 4 + j;
            oc[t * DD + e] = oacc[n][j] * invs[j];
        }
    }
}

// ---------------------------------------------------------------------------
extern "C" void kernel_launch(void* const* d_in, const int* in_sizes, int n_in,
                              void* d_out, int out_size, void* d_ws, size_t ws_size,
                              hipStream_t stream) {
    const float* q  = (const float*)d_in[0];
    const float* k  = (const float*)d_in[1];
    const float* v  = (const float*)d_in[2];
    const float* W  = (const float*)d_in[3];
    const float* bi = (const float*)d_in[4];
    float* out = (float*)d_out;

    float* zc_g = (float*)d_ws;                         // 16384 f32
    float* zp_g = zc_g + (size_t)NCHKS * DD;            // 16384 f32
    short* Ss_g = (short*)(zp_g + (size_t)NCHKS * DD);  // 4 MB
    short* Sp_g = Ss_g + (size_t)NCHKS * DD * DD;       // 4 MB
    short* vT_g = Sp_g + (size_t)NCHKS * DD * DD;       // 2 MB
    short* Kf_g = vT_g + (size_t)NCHKS * DD * CHK;      // 2 MB

    k1_chunk<<<2 * NCHKS, 256, 0, stream>>>(k, v, W, bi, Ss_g, zc_g, vT_g, Kf_g);
    k2_scan<<<512, 128, 0, stream>>>(Ss_g, zc_g, Sp_g, zp_g);
    k3_out<<<2 * NCHKS, 256, 0, stream>>>(q, W, bi, Kf_g, Sp_g, zp_g, vT_g, out);
}

// Round 7
// 27.306 us; speedup vs baseline: 1.1756x; 1.0394x over previous
//
#include <hip/hip_runtime.h>
#include <hip/hip_bf16.h>

#define BB 4
#define TT 2048
#define DD 128
#define CHK 64
#define NCHK 32            // TT/CHK
#define NCHKS (BB*NCHK)    // 128 chunks total

typedef __attribute__((ext_vector_type(8))) short  bf16x8;
typedef __attribute__((ext_vector_type(4))) float  f32x4;

#define MFMA(a,b,c) __builtin_amdgcn_mfma_f32_16x16x32_bf16(a, b, c, 0, 0, 0)

__device__ __forceinline__ short f2b(float f) {
    union { float f; unsigned u; } x; x.f = f;
    unsigned r = x.u + 0x7fffu + ((x.u >> 16) & 1u);   // RNE
    return (short)(r >> 16);
}
__device__ __forceinline__ float b2f(short s) {
    union { unsigned u; float f; } x; x.u = ((unsigned)(unsigned short)s) << 16;
    return x.f;
}
__device__ __forceinline__ bf16x8 cvt8(const float* p) {
    float4 a = *(const float4*)p, b = *(const float4*)(p + 4);
    bf16x8 r;
    r[0]=f2b(a.x); r[1]=f2b(a.y); r[2]=f2b(a.z); r[3]=f2b(a.w);
    r[4]=f2b(b.x); r[5]=f2b(b.y); r[6]=f2b(b.z); r[7]=f2b(b.w);
    return r;
}

// ---------------------------------------------------------------------------
// K1: block (c, h): phi(k) full -> KfT (for S-GEMM);
//     h==0: stage Kf row-major -> global, z_c.
//     h==1: phi(q) full, stage Qf row-major -> global.
//     vT half -> global; S_half = Kf^T V_half -> Ss_g bf16 [c][e][d].
// grid 256 x 256. LDS ~79.9 KB -> 2 blocks/CU.
// ---------------------------------------------------------------------------
__global__ __launch_bounds__(256) void k1_chunk(const float* __restrict__ q,
                                                const float* __restrict__ kin,
                                                const float* __restrict__ vin,
                                                const float* __restrict__ W,
                                                const float* __restrict__ bias,
                                                short* __restrict__ Ss_g,
                                                float* __restrict__ zc_g,
                                                short* __restrict__ vT_g,
                                                short* __restrict__ Qf_g,
                                                short* __restrict__ Kf_g) {
    int c = blockIdx.x >> 1, h = blockIdx.x & 1;
    const float* qc = q   + (size_t)c * CHK * DD;
    const float* kc = kin + (size_t)c * CHK * DD;
    const float* vc = vin + (size_t)c * CHK * DD;

    __shared__ __align__(16) short Wl  [DD][DD + 8];    // 34816 B
    __shared__ __align__(16) short KfT [DD][CHK + 8];   // 18432 B  (KfT[d][t])
    __shared__ __align__(16) short vT  [CHK][CHK + 8];  // 9216 B   (vT[e_local][t])
    __shared__ __align__(16) short stage[CHK][DD + 8];  // 17408 B  Qf/Kf rowmajor, then Ss bf16

    int tid = threadIdx.x, lane = tid & 63, w = tid >> 6;
    int l15 = lane & 15, l4 = lane >> 4;
    const f32x4 z4 = {0.f, 0.f, 0.f, 0.f};

    // prefetch A-fragments (k always; q on h==1)
    bf16x8 afk[4], afq[4];
    {
        int row = 16 * w + l15;
        #pragma unroll
        for (int kk = 0; kk < 4; ++kk) afk[kk] = cvt8(kc + row * DD + kk * 32 + l4 * 8);
        if (h) {
            #pragma unroll
            for (int kk = 0; kk < 4; ++kk) afq[kk] = cvt8(qc + row * DD + kk * 32 + l4 * 8);
        }
    }
    // W fp32 -> LDS bf16 (padded rows)
    #pragma unroll
    for (int it = 0; it < 16; ++it) {
        int i = tid + it * 256;               // 4096 float4s
        int row = i >> 5, c4 = (i & 31) * 4;
        float4 v = *(const float4*)(W + (size_t)row * DD + c4);
        unsigned lo = (unsigned short)f2b(v.x) | ((unsigned)(unsigned short)f2b(v.y) << 16);
        unsigned hi = (unsigned short)f2b(v.z) | ((unsigned)(unsigned short)f2b(v.w) << 16);
        uint2 p; p.x = lo; p.y = hi;
        *(uint2*)&Wl[row][c4] = p;
    }
    // vT half: v[t][64h + e_local] -> vT[e_local][t]
    #pragma unroll
    for (int it = 0; it < 4; ++it) {
        int i = tid + it * 256;               // 1024 float4s
        int t = i >> 4, c4 = (i & 15) * 4;
        float4 vv = *(const float4*)(vc + t * DD + 64 * h + c4);
        vT[c4 + 0][t] = f2b(vv.x); vT[c4 + 1][t] = f2b(vv.y);
        vT[c4 + 2][t] = f2b(vv.z); vT[c4 + 3][t] = f2b(vv.w);
    }
    __syncthreads();

    // phi(k): wave w -> t rows 16w..16w+15, all e
    #pragma unroll
    for (int n = 0; n < 8; ++n) {
        int e = 16 * n + l15;
        f32x4 d = z4;
        #pragma unroll
        for (int kk = 0; kk < 4; ++kk) {
            bf16x8 bw = *(const bf16x8*)&Wl[e][kk * 32 + l4 * 8];
            d = MFMA(afk[kk], bw, d);
        }
        float bv = bias[e];
        #pragma unroll
        for (int j = 0; j < 4; ++j) {
            float zv = d[j] + bv;
            short r = f2b((zv > 0.f) ? (zv + 1.f) : __expf(zv));   // ELU+1
            int t = 16 * w + l4 * 4 + j;
            KfT[e][t] = r;
            if (h == 0) stage[t][e] = r;       // Kf row-major
        }
    }
    // phi(q) (h==1) -> stage row-major
    if (h) {
        #pragma unroll
        for (int n = 0; n < 8; ++n) {
            int e = 16 * n + l15;
            f32x4 d = z4;
            #pragma unroll
            for (int kk = 0; kk < 4; ++kk) {
                bf16x8 bw = *(const bf16x8*)&Wl[e][kk * 32 + l4 * 8];
                d = MFMA(afq[kk], bw, d);
            }
            float bv = bias[e];
            #pragma unroll
            for (int j = 0; j < 4; ++j) {
                float zv = d[j] + bv;
                stage[16 * w + l4 * 4 + j][e] = f2b((zv > 0.f) ? (zv + 1.f) : __expf(zv));
            }
        }
    }
    __syncthreads();

    // stage -> global (h: Qf, else Kf), coalesced
    {
        short* dst = (h ? Qf_g : Kf_g) + (size_t)c * CHK * DD;
        #pragma unroll
        for (int it = 0; it < 4; ++it) {
            int i = tid + it * 256;           // 1024 bf16x8 units
            int t = i >> 4, u = (i & 15) * 8;
            *(bf16x8*)(dst + t * DD + u) = *(const bf16x8*)&stage[t][u];
        }
    }
    // z_c (h==0)
    if (h == 0 && tid < DD) {
        float s = 0.f;
        #pragma unroll
        for (int t8 = 0; t8 < CHK / 8; ++t8) {
            bf16x8 kv = *(const bf16x8*)&KfT[tid][t8 * 8];
            #pragma unroll
            for (int j = 0; j < 8; ++j) s += b2f(kv[j]);
        }
        zc_g[(size_t)c * DD + tid] = s;
    }
    // vT half -> global [c][e][t]
    #pragma unroll
    for (int it = 0; it < 2; ++it) {
        int i = tid + it * 256;               // 512 bf16x8
        int e = i >> 3, t0 = (i & 7) * 8;
        *(bf16x8*)(vT_g + (size_t)c * DD * CHK + (64 * h + e) * CHK + t0) =
            *(const bf16x8*)&vT[e][t0];
    }

    // S-GEMM half: S[d][e_local] = sum_t KfT[d][t] * vT[e_local][t]
    f32x4 sacc[2][4];
    #pragma unroll
    for (int mi = 0; mi < 2; ++mi)
        #pragma unroll
        for (int n = 0; n < 4; ++n) sacc[mi][n] = z4;
    #pragma unroll
    for (int kk = 0; kk < 2; ++kk) {
        bf16x8 afr[2];
        #pragma unroll
        for (int mi = 0; mi < 2; ++mi)
            afr[mi] = *(const bf16x8*)&KfT[16 * (2 * w + mi) + l15][kk * 32 + l4 * 8];
        #pragma unroll
        for (int n = 0; n < 4; ++n) {
            bf16x8 bfr = *(const bf16x8*)&vT[16 * n + l15][kk * 32 + l4 * 8];
            sacc[0][n] = MFMA(afr[0], bfr, sacc[0][n]);
            sacc[1][n] = MFMA(afr[1], bfr, sacc[1][n]);
        }
    }
    __syncthreads();   // stage copy-out done; safe to overwrite

    // sacc -> stage as bf16 Ss[e_local][d]
    #pragma unroll
    for (int mi = 0; mi < 2; ++mi)
        #pragma unroll
        for (int n = 0; n < 4; ++n) {
            int e = 16 * n + l15;
            #pragma unroll
            for (int j = 0; j < 4; ++j)
                stage[e][16 * (2 * w + mi) + l4 * 4 + j] = f2b(sacc[mi][n][j]);
        }
    __syncthreads();

    // stage -> Ss_g bf16 [c][64h+e][d]
    short* dst = Ss_g + (size_t)c * DD * DD + (size_t)(64 * h) * DD;
    #pragma unroll
    for (int it = 0; it < 4; ++it) {
        int i = tid + it * 256;               // 1024 bf16x8
        int e = i >> 4, u = (i & 15) * 8;
        *(bf16x8*)(dst + e * DD + u) = *(const bf16x8*)&stage[e][u];
    }
}

// ---------------------------------------------------------------------------
// K2: exclusive prefix over chunks (bf16 in/out, fp32 accum).
// grid 512 = (b,e) x 128 thr (thread = d).
// ---------------------------------------------------------------------------
__global__ __launch_bounds__(128) void k2_scan(const short* __restrict__ Ss_g,
                                               const float* __restrict__ zc_g,
                                               short* __restrict__ Sp_g,
                                               float* __restrict__ zp_g) {
    int e = blockIdx.x & 127, b = blockIdx.x >> 7;
    int d = threadIdx.x;
    size_t base = ((size_t)(b * NCHK) * DD + e) * DD + d;
    const size_t stride = (size_t)DD * DD;

    float vals[NCHK];
    #pragma unroll
    for (int c2 = 0; c2 < NCHK; ++c2) vals[c2] = b2f(Ss_g[base + c2 * stride]);
    float run = 0.f;
    #pragma unroll
    for (int c2 = 0; c2 < NCHK; ++c2) {
        Sp_g[base + c2 * stride] = f2b(run);
        run += vals[c2];
    }
    if (e == 0) {
        float vz[NCHK];
        #pragma unroll
        for (int c2 = 0; c2 < NCHK; ++c2) vz[c2] = zc_g[(size_t)(b * NCHK + c2) * DD + d];
        float rz = 0.f;
        #pragma unroll
        for (int c2 = 0; c2 < NCHK; ++c2) {
            zp_g[(size_t)(b * NCHK + c2) * DD + d] = rz;
            rz += vz[c2];
        }
    }
}

// ---------------------------------------------------------------------------
// K3: block (c, h): pure epilogue. Qf, Kf coalesced global -> LDS.
//     P=QK^T causal -> Ps bf16; den (wave0); out half = Ps@V + Q@Sp; store.
// grid 256 x 256. LDS ~44.8 KB.
// ---------------------------------------------------------------------------
__global__ __launch_bounds__(256) void k3_out(const short* __restrict__ Qf_g,
                                              const short* __restrict__ Kf_g,
                                              const short* __restrict__ Sp_g,
                                              const float* __restrict__ zp_g,
                                              const short* __restrict__ vT_g,
                                              float* __restrict__ out) {
    int c = blockIdx.x >> 1, h = blockIdx.x & 1;

    __shared__ __align__(16) short Qf[CHK][DD + 8];    // 17408 B
    __shared__ __align__(16) short Kf[CHK][DD + 8];    // 17408 B
    __shared__ __align__(16) short Ps[CHK][CHK + 8];   // 9216 B
    __shared__ float zs[DD];
    __shared__ float den[CHK];

    int tid = threadIdx.x, lane = tid & 63, w = tid >> 6;
    int l15 = lane & 15, l4 = lane >> 4;
    const f32x4 z4 = {0.f, 0.f, 0.f, 0.f};

    if (tid < DD) zs[tid] = zp_g[(size_t)c * DD + tid];

    // Qf, Kf global -> LDS (coalesced)
    {
        const short* srcq = Qf_g + (size_t)c * CHK * DD;
        const short* srck = Kf_g + (size_t)c * CHK * DD;
        #pragma unroll
        for (int it = 0; it < 4; ++it) {
            int i = tid + it * 256;           // 1024 bf16x8
            int t = i >> 4, u = (i & 15) * 8;
            *(bf16x8*)&Qf[t][u] = *(const bf16x8*)(srcq + t * DD + u);
            *(bf16x8*)&Kf[t][u] = *(const bf16x8*)(srck + t * DD + u);
        }
    }
    __syncthreads();

    // QK^T causal -> Ps
    bf16x8 aq[4];
    #pragma unroll
    for (int kk = 0; kk < 4; ++kk)
        aq[kk] = *(const bf16x8*)&Qf[16 * w + l15][kk * 32 + l4 * 8];
    #pragma unroll
    for (int n2 = 0; n2 < 4; ++n2) {
        f32x4 p = z4;
        #pragma unroll
        for (int kk = 0; kk < 4; ++kk) {
            bf16x8 bk = *(const bf16x8*)&Kf[16 * n2 + l15][kk * 32 + l4 * 8];
            p = MFMA(aq[kk], bk, p);
        }
        int t2 = 16 * n2 + l15;
        #pragma unroll
        for (int j = 0; j < 4; ++j) {
            int t = 16 * w + l4 * 4 + j;
            Ps[t][t2] = (t2 <= t) ? f2b(p[j]) : (short)0;
        }
    }
    __syncthreads();

    // den (wave 0)
    if (tid < CHK) {
        float s = 1e-6f;
        #pragma unroll
        for (int t8 = 0; t8 < CHK / 8; ++t8) {
            bf16x8 pv = *(const bf16x8*)&Ps[tid][t8 * 8];
            #pragma unroll
            for (int j = 0; j < 8; ++j) s += b2f(pv[j]);
        }
        #pragma unroll
        for (int d8 = 0; d8 < DD / 8; ++d8) {
            bf16x8 qv = *(const bf16x8*)&Qf[tid][d8 * 8];
            #pragma unroll
            for (int j = 0; j < 8; ++j) s += b2f(qv[j]) * zs[d8 * 8 + j];
        }
        den[tid] = s;
    }

    // out half: e = 64h + 16n + l15, n = 0..3
    bf16x8 ap[2];
    #pragma unroll
    for (int kk = 0; kk < 2; ++kk)
        ap[kk] = *(const bf16x8*)&Ps[16 * w + l15][kk * 32 + l4 * 8];

    const short* Sp  = Sp_g + (size_t)c * DD * DD;
    const short* vTg = vT_g + (size_t)c * DD * CHK;
    f32x4 oacc[4];
    #pragma unroll
    for (int n = 0; n < 4; ++n) oacc[n] = z4;
    #pragma unroll
    for (int n = 0; n < 4; ++n) {
        int e = 64 * h + 16 * n + l15;
        #pragma unroll
        for (int kk = 0; kk < 4; ++kk) {
            bf16x8 bs = *(const bf16x8*)(Sp + e * DD + kk * 32 + l4 * 8);
            oacc[n] = MFMA(aq[kk], bs, oacc[n]);
        }
        #pragma unroll
        for (int kk = 0; kk < 2; ++kk) {
            bf16x8 bv = *(const bf16x8*)(vTg + e * CHK + kk * 32 + l4 * 8);
            oacc[n] = MFMA(ap[kk], bv, oacc[n]);
        }
    }
    __syncthreads();   // den ready

    float* oc = out + (size_t)c * CHK * DD;
    float invs[4];
    #pragma unroll
    for (int j = 0; j < 4; ++j) invs[j] = 1.0f / den[16 * w + l4 * 4 + j];
    #pragma unroll
    for (int n = 0; n < 4; ++n) {
        int e = 64 * h + 16 * n + l15;
        #pragma unroll
        for (int j = 0; j < 4; ++j) {
            int t = 16 * w + l4 * 4 + j;
            oc[t * DD + e] = oacc[n][j] * invs[j];
        }
    }
}

// ---------------------------------------------------------------------------
extern "C" void kernel_launch(void* const* d_in, const int* in_sizes, int n_in,
                              void* d_out, int out_size, void* d_ws, size_t ws_size,
                              hipStream_t stream) {
    const float* q  = (const float*)d_in[0];
    const float* k  = (const float*)d_in[1];
    const float* v  = (const float*)d_in[2];
    const float* W  = (const float*)d_in[3];
    const float* bi = (const float*)d_in[4];
    float* out = (float*)d_out;

    float* zc_g = (float*)d_ws;                         // 16384 f32
    float* zp_g = zc_g + (size_t)NCHKS * DD;            // 16384 f32
    short* Ss_g = (short*)(zp_g + (size_t)NCHKS * DD);  // 4 MB
    short* Sp_g = Ss_g + (size_t)NCHKS * DD * DD;       // 4 MB
    short* vT_g = Sp_g + (size_t)NCHKS * DD * DD;       // 2 MB
    short* Qf_g = vT_g + (size_t)NCHKS * DD * CHK;      // 2 MB
    short* Kf_g = Qf_g + (size_t)NCHKS * CHK * DD;      // 2 MB

    k1_chunk<<<2 * NCHKS, 256, 0, stream>>>(q, k, v, W, bi, Ss_g, zc_g, vT_g, Qf_g, Kf_g);
    k2_scan<<<512, 128, 0, stream>>>(Ss_g, zc_g, Sp_g, zp_g);
    k3_out<<<2 * NCHKS, 256, 0, stream>>>(Qf_g, Kf_g, Sp_g, zp_g, vT_g, out);
}